// Round 4
// baseline (98.723 us; speedup 1.0000x reference)
//
#include <hip/hip_runtime.h>

#define POOL 100
#define PLEN 8
#define EMB 768
#define KEYD 768
#define BATCH 256
#define LD (PLEN*EMB)              // 6144
#define EK_FLOATS (BATCH*4*EMB)    // 786432
#define XB_FLOATS (BATCH*197*EMB)  // 38756352
#define LOSS_OFF (2*EK_FLOATS)     // 1572864
#define XB_OFF (LOSS_OFF+1)        // 1572865 (4B-aligned only!)
#define NGRAM 5050                 // 100*101/2 triangular pairs
#define NCOS (BATCH*25)            // 6400 blocks, 4 waves x 25 k's each
#define N4 9689087                 // (XB_FLOATS-3)/4 aligned float4 in copy
#define TILE 2048                  // float4 per copy block (256 thr x 8 iters)
#define NCOPY1 2600                // copy tiles in kernel A (55%)
#define NCOPY2 2131                // remaining tiles in kernel B

typedef float v4f __attribute__((ext_vector_type(4)));

// Both-sides-16B-aligned streaming copy tile. dst4[j] = {src4[j].w, src4[j+1].xyz};
// src4[j].w comes from the wave neighbor via shfl_up (wave-lane 0: scalar load).
// Nontemporal on both sides: xb/out are touched exactly once, keep L2/L3 for p/K/G.
__device__ __forceinline__ void copy_tile(const float* __restrict__ xb,
                                          float* __restrict__ out, int tile) {
    const v4f* src4 = (const v4f*)xb;                // 16B aligned
    v4f* dst4 = (v4f*)(out + XB_OFF + 3);            // 16B aligned
    size_t base = (size_t)tile * TILE + threadIdx.x;
    #pragma unroll
    for (int it = 0; it < 8; ++it) {
        size_t j = base + (size_t)it * 256;
        if (j < N4) {
            v4f v = __builtin_nontemporal_load(&src4[j + 1]);
            float pw = __shfl_up(v[3], 1, 64);       // neighbor's src4[j].w
            if ((threadIdx.x & 63) == 0) pw = xb[4 * j + 3];
            v4f o = {pw, v[0], v[1], v[2]};
            __builtin_nontemporal_store(o, &dst4[j]);
        }
    }
}

// Kernel A: copy chunk A (blocks first -> HBM saturates immediately),
// then gram pairs, then cos rows. Also inits loss accumulators + head/tail scalars.
__global__ void kA(const float* __restrict__ p, const float* __restrict__ xq,
                   const float* __restrict__ K, const float* __restrict__ xb,
                   float* __restrict__ out, double* __restrict__ G,
                   double* __restrict__ cosm, double* __restrict__ lossAcc,
                   unsigned int* __restrict__ lossCnt) {
    int t = blockIdx.x;
    if (t < NCOPY1) {
        if (t == 0) {
            if (threadIdx.x == 64) { lossAcc[0] = 0.0; lossCnt[0] = 0u; }
            if (threadIdx.x == 65) {
                out[XB_OFF]     = xb[0];
                out[XB_OFF + 1] = xb[1];
                out[XB_OFF + 2] = xb[2];
                out[XB_OFF + XB_FLOATS - 1] = xb[XB_FLOATS - 1];
            }
        }
        copy_tile(xb, out, t);
        return;
    }
    t -= NCOPY1;
    if (t < NGRAM) {
        // triangular index -> (kx,ky), ky <= kx
        int kx = (int)((sqrt(8.0 * t + 1.0) - 1.0) * 0.5);
        while ((kx + 1) * (kx + 2) / 2 <= t) ++kx;
        while (kx * (kx + 1) / 2 > t) --kx;
        int ky = t - kx * (kx + 1) / 2;
        const v4f* a = (const v4f*)(p + (size_t)kx * LD);
        const v4f* b = (const v4f*)(p + (size_t)ky * LD);
        double acc = 0.0;
        #pragma unroll
        for (int it = 0; it < 6; ++it) {             // 1536 float4 / 256 thr
            int j = it * 256 + threadIdx.x;
            v4f va = a[j], vb = b[j];
            acc += (double)va[0]*vb[0] + (double)va[1]*vb[1]
                 + (double)va[2]*vb[2] + (double)va[3]*vb[3];
        }
        for (int off = 32; off > 0; off >>= 1) acc += __shfl_down(acc, off, 64);
        __shared__ double s[4];
        int lane = threadIdx.x & 63, w = threadIdx.x >> 6;
        if (lane == 0) s[w] = acc;
        __syncthreads();
        if (threadIdx.x == 0) {
            double v = s[0] + s[1] + s[2] + s[3];
            G[ky * POOL + kx] = v;
            G[kx * POOL + ky] = v;
        }
    } else {
        int c = t - NGRAM;
        int b = c / 25, kg = c % 25;
        int w = threadIdx.x >> 6, lane = threadIdx.x & 63;
        int k = kg * 4 + w;                          // < 100 always
        const v4f* kr = (const v4f*)(K + (size_t)k * KEYD);
        const v4f* xr = (const v4f*)(xq + (size_t)b * KEYD);
        double dot = 0.0, sq = 0.0;
        #pragma unroll
        for (int it = 0; it < 3; ++it) {             // 192 float4 per row
            v4f a = kr[it * 64 + lane];
            v4f x = xr[it * 64 + lane];
            dot += (double)a[0]*x[0] + (double)a[1]*x[1] + (double)a[2]*x[2] + (double)a[3]*x[3];
            sq  += (double)a[0]*a[0] + (double)a[1]*a[1] + (double)a[2]*a[2] + (double)a[3]*a[3];
        }
        for (int off = 32; off > 0; off >>= 1) {
            dot += __shfl_down(dot, off, 64);
            sq  += __shfl_down(sq,  off, 64);
        }
        if (lane == 0)
            cosm[(size_t)b * POOL + k] = dot / fmax(sqrt(sq), 1e-12);
    }
}

// Kernel B: blocks [0,BATCH) = per-b vq (softmax/cross/argmin/loss/gather),
// blocks [BATCH, BATCH+NCOPY2) = copy chunk B. vq hides under copy BW.
__global__ void kB(const double* __restrict__ cosm, const double* __restrict__ G,
                   const float* __restrict__ p, const float* __restrict__ xb,
                   float* __restrict__ out, double* __restrict__ lossAcc,
                   unsigned int* __restrict__ lossCnt) {
    if (blockIdx.x >= BATCH) {
        copy_tile(xb, out, NCOPY1 + (int)(blockIdx.x - BATCH));
        return;
    }
    int b = blockIdx.x;
    __shared__ double sa[POOL], sm[POOL];
    __shared__ double sred[4];
    __shared__ int sidx;
    int lane = threadIdx.x & 63, w = threadIdx.x >> 6;

    double cv = (threadIdx.x < POOL) ? cosm[(size_t)b * POOL + threadIdx.x] : -1.0e300;
    // block max
    double m = cv;
    for (int off = 32; off > 0; off >>= 1) m = fmax(m, __shfl_down(m, off, 64));
    if (lane == 0) sred[w] = m;
    __syncthreads();
    m = fmax(fmax(sred[0], sred[1]), fmax(sred[2], sred[3]));
    __syncthreads();
    // exp + block sum
    double e = (threadIdx.x < POOL) ? exp(cv - m) : 0.0;
    double ssum = e;
    for (int off = 32; off > 0; off >>= 1) ssum += __shfl_down(ssum, off, 64);
    if (lane == 0) sred[w] = ssum;
    __syncthreads();
    ssum = sred[0] + sred[1] + sred[2] + sred[3];
    __syncthreads();
    if (threadIdx.x < POOL) sa[threadIdx.x] = e / ssum;   // alpha
    __syncthreads();
    // cross + per-k dist term
    double c = 0.0, paterm = 0.0;
    if (threadIdx.x < POOL) {
        #pragma unroll 4
        for (int k = 0; k < POOL; ++k)
            c += sa[k] * G[k * POOL + threadIdx.x];       // coalesced over tid
        paterm = sa[threadIdx.x] * c;
        sm[threadIdx.x] = G[threadIdx.x * POOL + threadIdx.x] - 2.0 * c;
    }
    // pa_sq block sum
    double pa = paterm;
    for (int off = 32; off > 0; off >>= 1) pa += __shfl_down(pa, off, 64);
    if (lane == 0) sred[w] = pa;
    __syncthreads();                                       // also fences sm[]
    pa = sred[0] + sred[1] + sred[2] + sred[3];
    if (threadIdx.x == 0) {
        int best = 0; double bm = sm[0];
        for (int k = 1; k < POOL; ++k)
            if (sm[k] < bm) { bm = sm[k]; best = k; }      // first-index tiebreak = np.argmin
        sidx = best;
        double dterm = pa + bm;    // = pa_sq - 2*cross[idx] + pp_sq[idx]
        atomicAdd(lossAcc, dterm);
        __threadfence();
        unsigned int old = atomicAdd(lossCnt, 1u);
        if (old == BATCH - 1) {
            double total = atomicAdd(lossAcc, 0.0);        // fresh read
            double msq = total / (double)(BATCH * PLEN * EMB);
            out[LOSS_OFF] = (float)(0.5 * msq);            // 0.4*e + 0.1*q, e==q numerically
        }
    }
    __syncthreads();
    int idx = sidx;
    const float4* src = (const float4*)(p + (size_t)idx * LD);
    float4* ek = (float4*)out;
    float4* ev = (float4*)(out + EK_FLOATS);
    for (int j = threadIdx.x; j < LD / 4; j += 256) {      // 1536 float4
        float4 v = src[j];
        int l = j / (EMB / 4);        // prompt-slot 0..7
        int r = j % (EMB / 4);
        if (l < 4) ek[b * EMB + l * (EMB / 4) + r] = v;
        else       ev[b * EMB + (l - 4) * (EMB / 4) + r] = v;
    }
}

extern "C" void kernel_launch(void* const* d_in, const int* in_sizes, int n_in,
                              void* d_out, int out_size, void* d_ws, size_t ws_size,
                              hipStream_t stream) {
    const float* xq = (const float*)d_in[0];
    // d_in[1] = l (always 0, in E_LAYERS)
    const float* xb = (const float*)d_in[2];
    const float* K  = (const float*)d_in[3];
    const float* p  = (const float*)d_in[4];
    float* out = (float*)d_out;

    double* G        = (double*)d_ws;          // 100*100 doubles = 80 KB
    double* cosm     = G + POOL * POOL;        // 256*100 doubles = 200 KB
    double* lossAcc  = cosm + BATCH * POOL;    // 1 double
    unsigned int* lossCnt = (unsigned int*)(lossAcc + 1);

    kA<<<NCOPY1 + NGRAM + NCOS, 256, 0, stream>>>(p, xq, K, xb, out, G, cosm, lossAcc, lossCnt);
    kB<<<BATCH + NCOPY2, 256, 0, stream>>>(cosm, G, p, xb, out, lossAcc, lossCnt);
}